// Round 4
// baseline (353.255 us; speedup 1.0000x reference)
//
#include <hip/hip_runtime.h>
#include <hip/hip_bf16.h>

// Problem constants
#define T_DIM 2048
#define B_DIM 8
#define D_DIM 1024
#define M_DIM (T_DIM * B_DIM)     // 16384
#define K_DIM D_DIM               // 1024
#define NW_DIM (2 * D_DIM)        // 2048 combined GEMM cols (alpha | v)
#define NCH (B_DIM * D_DIM)       // 8192 channels
#define NCH4 (NCH / 4)            // 2048 float4 channels

// fp32 fallback scan config (round-3 known-good)
#define CHUNKS 64
#define CHUNK_LEN 32
// bf16 fast-path scan config
#define BCHUNKS 128
#define BCLEN 16

typedef __attribute__((ext_vector_type(8))) short bf16x8;
typedef __attribute__((ext_vector_type(4))) float f32x4;

__device__ __forceinline__ unsigned short bf16_rne(float f) {
    unsigned u = __float_as_uint(f);
    unsigned r = u + 0x7fffu + ((u >> 16) & 1u);
    return (unsigned short)(r >> 16);
}

__device__ __forceinline__ float bf16_to_f32(unsigned short u) {
    return __uint_as_float(((unsigned)u) << 16);
}

__device__ __forceinline__ float sigmoidf(float z) {
    return 1.0f / (1.0f + __expf(-z));
}

__device__ __forceinline__ void load_lds16(const void* g, void* l) {
    __builtin_amdgcn_global_load_lds(
        (const __attribute__((address_space(1))) void*)g,
        (__attribute__((address_space(3))) void*)l,
        16, 0, 0);
}

// ---------------- fp32 -> bf16 convert (x) ----------------
__global__ void f32_to_bf16_kernel(const float4* __restrict__ in,
                                   ushort4* __restrict__ out, int n4) {
    int i = blockIdx.x * blockDim.x + threadIdx.x;
    if (i < n4) {
        float4 f = in[i];
        ushort4 o;
        o.x = bf16_rne(f.x);
        o.y = bf16_rne(f.y);
        o.z = bf16_rne(f.z);
        o.w = bf16_rne(f.w);
        out[i] = o;
    }
}

// ---------------- weights convert: Wcat = [Wa ; Wv] bf16 ----------------
__global__ void conv_weights_kernel(const float4* __restrict__ Wa,
                                    const float4* __restrict__ Wv,
                                    ushort4* __restrict__ Wcat) {
    const int half4 = D_DIM * D_DIM / 4;  // 262144
    int i = blockIdx.x * blockDim.x + threadIdx.x;  // 0 .. 2*half4-1
    float4 f = (i < half4) ? Wa[i] : Wv[i - half4];
    ushort4 o;
    o.x = bf16_rne(f.x);
    o.y = bf16_rne(f.y);
    o.z = bf16_rne(f.z);
    o.w = bf16_rne(f.w);
    Wcat[i] = o;
}

// ---------------- fused bf16 MFMA GEMM ----------------
// A: [M,K] bf16 row-major.  Wcat: [2048,1024] bf16 row-major (B^T layout).
// cols [0,1024): alpha = sigmoid(xWa^T + ba); cols [1024,2048): v = xWv^T+bv.
// BF16OUT=1: write bf16 into a16/v16 (stride 1024). Else fp32 alpha_f/v_f.
// 128x128 tile, BK=64, 4 waves 2x2, wave = 4x4 of 16x16x32 MFMAs.
// XOR-swizzled LDS (conflict-free; verified SQ_LDS_BANK_CONFLICT==0).
template <int BF16OUT>
__global__ __launch_bounds__(256) void gemm_fused_kernel(
    const unsigned short* __restrict__ A,
    const unsigned short* __restrict__ W,
    const float* __restrict__ ba,
    const float* __restrict__ bv,
    float* __restrict__ alpha_f, float* __restrict__ v_f,
    unsigned short* __restrict__ a16, unsigned short* __restrict__ v16) {
    __shared__ __attribute__((aligned(16))) unsigned short As[128 * 64];
    __shared__ __attribute__((aligned(16))) unsigned short Bs[128 * 64];

    const int tid = threadIdx.x;
    const int lane = tid & 63;
    const int w = tid >> 6;
    const int wm = w >> 1;
    const int wn = w & 1;
    const int quad = lane >> 4;
    const int l16 = lane & 15;
    const int xr = l16 & 7;

    const int bm = blockIdx.y * 128;
    const int bn = blockIdx.x * 128;

    const int st_row = lane >> 3;
    const int st_col = ((lane & 7) ^ st_row) * 8;

    f32x4 zero = {0.f, 0.f, 0.f, 0.f};
    f32x4 acc[4][4];
#pragma unroll
    for (int i = 0; i < 4; ++i)
#pragma unroll
        for (int j = 0; j < 4; ++j) acc[i][j] = zero;

    for (int kt = 0; kt < K_DIM / 64; ++kt) {
        const int k0 = kt * 64;
#pragma unroll
        for (int j = 0; j < 4; ++j) {
            const int r = w * 32 + j * 8;
            load_lds16(A + (size_t)(bm + r + st_row) * K_DIM + k0 + st_col,
                       &As[r * 64]);
            load_lds16(W + (size_t)(bn + r + st_row) * K_DIM + k0 + st_col,
                       &Bs[r * 64]);
        }
        __syncthreads();
#pragma unroll
        for (int s = 0; s < 2; ++s) {
            bf16x8 af[4], bfr[4];
#pragma unroll
            for (int i = 0; i < 4; ++i)
                af[i] = *(const bf16x8*)&As[(wm * 64 + i * 16 + l16) * 64 +
                                            (((s * 4 + quad) ^ xr) * 8)];
#pragma unroll
            for (int i = 0; i < 4; ++i)
                bfr[i] = *(const bf16x8*)&Bs[(wn * 64 + i * 16 + l16) * 64 +
                                             (((s * 4 + quad) ^ xr) * 8)];
#pragma unroll
            for (int i = 0; i < 4; ++i)
#pragma unroll
                for (int j = 0; j < 4; ++j)
                    acc[i][j] = __builtin_amdgcn_mfma_f32_16x16x32_bf16(
                        af[i], bfr[j], acc[i][j], 0, 0, 0);
        }
        __syncthreads();
    }

    // epilogue: C/D layout col = lane&15, row = quad*4 + reg.
    const bool is_alpha = (bn < D_DIM);
    const float* __restrict__ bias = is_alpha ? ba : bv;
    const int nb = bn - (is_alpha ? 0 : D_DIM);
#pragma unroll
    for (int j = 0; j < 4; ++j) {
        const int n = nb + wn * 64 + j * 16 + l16;
        const float bias_n = bias[n];
#pragma unroll
        for (int i = 0; i < 4; ++i) {
            const int m0 = bm + wm * 64 + i * 16 + quad * 4;
#pragma unroll
            for (int r = 0; r < 4; ++r) {
                float val = acc[i][j][r] + bias_n;
                if (is_alpha) val = sigmoidf(val);
                if (BF16OUT) {
                    unsigned short* __restrict__ dst = is_alpha ? a16 : v16;
                    dst[(size_t)(m0 + r) * D_DIM + n] = bf16_rne(val);
                } else {
                    float* __restrict__ dst = is_alpha ? alpha_f : v_f;
                    dst[(size_t)(m0 + r) * D_DIM + n] = val;
                }
            }
        }
    }
}

// ================ bf16 fast-path scan (BCHUNKS=128, BCLEN=16) ================
// h_t = a_t*h_{t-1} + (1-a_t)*v_t == affine h_out = P*h_in + Q per chunk.

__global__ __launch_bounds__(256) void scan_phase1_bf16(
    const ushort4* __restrict__ ab,  // [T][NCH4] bf16x4
    const ushort4* __restrict__ vb,
    float4* __restrict__ P,          // [BCHUNKS][NCH4]
    float4* __restrict__ Q) {
    const int j4 = blockIdx.x * 256 + threadIdx.x;
    const int c = blockIdx.y;
    float4 Pr = {1.f, 1.f, 1.f, 1.f};
    float4 Qr = {0.f, 0.f, 0.f, 0.f};
    size_t base = (size_t)c * BCLEN * NCH4 + j4;
#pragma unroll
    for (int t = 0; t < BCLEN; ++t) {
        ushort4 au = ab[base + (size_t)t * NCH4];
        ushort4 vu = vb[base + (size_t)t * NCH4];
        float ax = bf16_to_f32(au.x), ay = bf16_to_f32(au.y),
              az = bf16_to_f32(au.z), aw = bf16_to_f32(au.w);
        float vx = bf16_to_f32(vu.x), vy = bf16_to_f32(vu.y),
              vz = bf16_to_f32(vu.z), vw = bf16_to_f32(vu.w);
        Pr.x *= ax; Pr.y *= ay; Pr.z *= az; Pr.w *= aw;
        Qr.x = ax * Qr.x + (1.f - ax) * vx;
        Qr.y = ay * Qr.y + (1.f - ay) * vy;
        Qr.z = az * Qr.z + (1.f - az) * vz;
        Qr.w = aw * Qr.w + (1.f - aw) * vw;
    }
    P[(size_t)c * NCH4 + j4] = Pr;
    Q[(size_t)c * NCH4 + j4] = Qr;
}

__global__ __launch_bounds__(256) void scan_phase2_bf16(
    const float4* __restrict__ P, const float4* __restrict__ Q,
    const float4* __restrict__ h0,
    float4* __restrict__ Hc) {  // [BCHUNKS][NCH4]
    const int j4 = blockIdx.x * 256 + threadIdx.x;
    float4 h = h0[j4];
#pragma unroll 8
    for (int c = 0; c < BCHUNKS; ++c) {
        Hc[(size_t)c * NCH4 + j4] = h;
        float4 p = P[(size_t)c * NCH4 + j4];
        float4 q = Q[(size_t)c * NCH4 + j4];
        h.x = p.x * h.x + q.x;
        h.y = p.y * h.y + q.y;
        h.z = p.z * h.z + q.z;
        h.w = p.w * h.w + q.w;
    }
}

__global__ __launch_bounds__(256) void scan_phase3_bf16(
    const ushort4* __restrict__ ab,
    const ushort4* __restrict__ vb,
    const float4* __restrict__ Hc,
    float4* __restrict__ out,    // [T][NCH4]
    float4* __restrict__ hout) { // h[t+1] slots: [T][NCH4]
    const int j4 = blockIdx.x * 256 + threadIdx.x;
    const int c = blockIdx.y;
    float4 h = Hc[(size_t)c * NCH4 + j4];
    size_t base = (size_t)c * BCLEN * NCH4 + j4;
#pragma unroll
    for (int t = 0; t < BCLEN; ++t) {
        ushort4 au = ab[base + (size_t)t * NCH4];
        ushort4 vu = vb[base + (size_t)t * NCH4];
        float ax = bf16_to_f32(au.x), ay = bf16_to_f32(au.y),
              az = bf16_to_f32(au.z), aw = bf16_to_f32(au.w);
        float vx = bf16_to_f32(vu.x), vy = bf16_to_f32(vu.y),
              vz = bf16_to_f32(vu.z), vw = bf16_to_f32(vu.w);
        h.x = ax * h.x + (1.f - ax) * vx;
        h.y = ay * h.y + (1.f - ay) * vy;
        h.z = az * h.z + (1.f - az) * vz;
        h.w = aw * h.w + (1.f - aw) * vw;
        float4 o;
        o.x = h.x * h.x * sigmoidf(h.x);
        o.y = h.y * h.y * sigmoidf(h.y);
        o.z = h.z * h.z * sigmoidf(h.z);
        o.w = h.w * h.w * sigmoidf(h.w);
        out[base + (size_t)t * NCH4] = o;
        hout[base + (size_t)t * NCH4] = h;
    }
}

// ================ fp32 fallback scan (round-3 known-good) ================
__global__ __launch_bounds__(256) void scan_phase1_kernel(
    const float4* __restrict__ alpha, const float4* __restrict__ v,
    float4* __restrict__ P, float4* __restrict__ Q) {
    const int j4 = blockIdx.x * 256 + threadIdx.x;
    const int c = blockIdx.y;
    float4 Pr = {1.f, 1.f, 1.f, 1.f};
    float4 Qr = {0.f, 0.f, 0.f, 0.f};
    size_t base = (size_t)c * CHUNK_LEN * NCH4 + j4;
#pragma unroll 4
    for (int t = 0; t < CHUNK_LEN; ++t) {
        float4 a = alpha[base + (size_t)t * NCH4];
        float4 vv = v[base + (size_t)t * NCH4];
        Pr.x *= a.x; Pr.y *= a.y; Pr.z *= a.z; Pr.w *= a.w;
        Qr.x = a.x * Qr.x + (1.f - a.x) * vv.x;
        Qr.y = a.y * Qr.y + (1.f - a.y) * vv.y;
        Qr.z = a.z * Qr.z + (1.f - a.z) * vv.z;
        Qr.w = a.w * Qr.w + (1.f - a.w) * vv.w;
    }
    P[(size_t)c * NCH4 + j4] = Pr;
    Q[(size_t)c * NCH4 + j4] = Qr;
}

__global__ __launch_bounds__(256) void scan_phase2_kernel(
    const float4* __restrict__ P, const float4* __restrict__ Q,
    const float4* __restrict__ h0, float4* __restrict__ Hc) {
    const int j4 = blockIdx.x * 256 + threadIdx.x;
    float4 h = h0[j4];
#pragma unroll 8
    for (int c = 0; c < CHUNKS; ++c) {
        Hc[(size_t)c * NCH4 + j4] = h;
        float4 p = P[(size_t)c * NCH4 + j4];
        float4 q = Q[(size_t)c * NCH4 + j4];
        h.x = p.x * h.x + q.x;
        h.y = p.y * h.y + q.y;
        h.z = p.z * h.z + q.z;
        h.w = p.w * h.w + q.w;
    }
}

__global__ __launch_bounds__(256) void scan_phase3_kernel(
    float4* __restrict__ alpha_out, float4* __restrict__ v_h,
    const float4* __restrict__ Hc) {
    const int j4 = blockIdx.x * 256 + threadIdx.x;
    const int c = blockIdx.y;
    float4 h = Hc[(size_t)c * NCH4 + j4];
    size_t base = (size_t)c * CHUNK_LEN * NCH4 + j4;
#pragma unroll 4
    for (int t = 0; t < CHUNK_LEN; ++t) {
        float4 a = alpha_out[base + (size_t)t * NCH4];
        float4 vv = v_h[base + (size_t)t * NCH4];
        h.x = a.x * h.x + (1.f - a.x) * vv.x;
        h.y = a.y * h.y + (1.f - a.y) * vv.y;
        h.z = a.z * h.z + (1.f - a.z) * vv.z;
        h.w = a.w * h.w + (1.f - a.w) * vv.w;
        float4 o;
        o.x = h.x * h.x * sigmoidf(h.x);
        o.y = h.y * h.y * sigmoidf(h.y);
        o.z = h.z * h.z * sigmoidf(h.z);
        o.w = h.w * h.w * sigmoidf(h.w);
        alpha_out[base + (size_t)t * NCH4] = o;
        v_h[base + (size_t)t * NCH4] = h;
    }
}

extern "C" void kernel_launch(void* const* d_in, const int* in_sizes, int n_in,
                              void* d_out, int out_size, void* d_ws, size_t ws_size,
                              hipStream_t stream) {
    const float* x  = (const float*)d_in[0];
    const float* h0 = (const float*)d_in[1];
    const float* Wa = (const float*)d_in[2];
    const float* ba = (const float*)d_in[3];
    const float* Wv = (const float*)d_in[4];
    const float* bv = (const float*)d_in[5];

    float* out = (float*)d_out;                   // output [T][NCH]
    float* hbase = out + (size_t)T_DIM * NCH;     // h [T+1][NCH]

    char* ws = (char*)d_ws;
    unsigned short* xb   = (unsigned short*)ws;                      // 32 MB
    unsigned short* Wcat = (unsigned short*)(ws + 33554432);         // 4 MB

    // convert inputs to bf16 (shared by both paths)
    f32_to_bf16_kernel<<<(M_DIM * K_DIM / 4) / 256, 256, 0, stream>>>(
        (const float4*)x, (ushort4*)xb, M_DIM * K_DIM / 4);
    conv_weights_kernel<<<(2 * D_DIM * D_DIM / 4) / 256, 256, 0, stream>>>(
        (const float4*)Wa, (const float4*)Wv, (ushort4*)Wcat);

    dim3 ggrid(NW_DIM / 128, M_DIM / 128);  // 2048 blocks
    hipMemcpyAsync(hbase, h0, (size_t)NCH * sizeof(float),
                   hipMemcpyDeviceToDevice, stream);

    if (ws_size >= 117440512) {
        // ---- bf16 fast path (needs 112 MB ws) ----
        unsigned short* a16 = (unsigned short*)(ws + 37748736);  // 32 MB @36M
        unsigned short* v16 = (unsigned short*)(ws + 71303168);  // 32 MB @68M
        float* P  = (float*)(ws + 104857600);                    // 4 MB @100M
        float* Q  = (float*)(ws + 109051904);                    // 4 MB @104M
        float* Hc = (float*)(ws + 113246208);                    // 4 MB @108M

        gemm_fused_kernel<1><<<ggrid, 256, 0, stream>>>(
            xb, Wcat, ba, bv, nullptr, nullptr, a16, v16);

        dim3 sgrid(NCH4 / 256, BCHUNKS);  // (8,128) = 1024 blocks
        scan_phase1_bf16<<<sgrid, 256, 0, stream>>>(
            (const ushort4*)a16, (const ushort4*)v16, (float4*)P, (float4*)Q);
        scan_phase2_bf16<<<NCH4 / 256, 256, 0, stream>>>(
            (const float4*)P, (const float4*)Q, (const float4*)h0, (float4*)Hc);
        scan_phase3_bf16<<<sgrid, 256, 0, stream>>>(
            (const ushort4*)a16, (const ushort4*)v16, (const float4*)Hc,
            (float4*)out, (float4*)(hbase + NCH));
    } else {
        // ---- fp32 fallback (round-3 path, 48 MB ws) ----
        float* alpha = out;            // temp alpha in output region
        float* vbuf = hbase + NCH;     // temp v in h[1..T]
        float* P  = (float*)(ws + 37748736);
        float* Q  = (float*)(ws + 39845888);
        float* Hc = (float*)(ws + 41943040);

        gemm_fused_kernel<0><<<ggrid, 256, 0, stream>>>(
            xb, Wcat, ba, bv, alpha, vbuf, nullptr, nullptr);

        dim3 sgrid(NCH4 / 256, CHUNKS);
        scan_phase1_kernel<<<sgrid, 256, 0, stream>>>(
            (const float4*)alpha, (const float4*)vbuf, (float4*)P, (float4*)Q);
        scan_phase2_kernel<<<NCH4 / 256, 256, 0, stream>>>(
            (const float4*)P, (const float4*)Q, (const float4*)h0, (float4*)Hc);
        scan_phase3_kernel<<<sgrid, 256, 0, stream>>>(
            (float4*)alpha, (float4*)vbuf, (const float4*)Hc);
    }
}